// Round 10
// baseline (383.302 us; speedup 1.0000x reference)
//
#include <hip/hip_runtime.h>
#include <hip/hip_fp16.h>

// NNUE forward: out = MLP(clip(concat(Wf@w_in^T+b, Bf@w_in^T+b)))
// Big GEMM: M=8192, N=256, K=40960, HBM-bound on the 1.31 GB A stream.
// fp16 MFMA 16x16x32, f32 accumulate.
//
// v8 (from r9: memory system at 2.9 TB/s vs 6.6 TB/s fill => DRAM burst
// inefficiency of 128B/row chunks at BK=32):
//  - A super-tiles of 128 k-floats: 512 B contiguous per row per fetch.
//    Reg chunks (4 float4/thread): issue at super s -> cvt+store at s+1 ->
//    consumed at s+2 (flight >= 2 subs).
//  - BK=64 sub-steps (160 barriers total), W via global_load_lds from
//    pre-swizzled 32 KB chunks, 3 buffers, staged 2 subs ahead.
//  - vmcnt(6) steady: {A(prev)x2, W(+2)x2, A(cur)x2} stay in flight.
//  - LDS 160 KB exact (A 2x32K + W 3x32K), 1 block/CU, 1024 thr, 16 waves.
//  - KS=4 -> 256 blocks; ks=blockIdx&3 -> one W slice per XCD.

#define FEAT 40960
#define PSTRIDE (8192ull * 256ull)
#define KS4 4
#define KCHUNK4 (FEAT / KS4)      // 10240
#define NSUPER 80                 // super-tiles of 128 k-floats
#define WCHUNK_BYTES 32768        // 256 rows x 64 k x f16, swizzled
#define NWCHUNK 640               // 40960/64
#define WWS_BYTES ((size_t)NWCHUNK * WCHUNK_BYTES)   // 20 MB

using floatx4 = __attribute__((ext_vector_type(4))) float;
using half8   = __attribute__((ext_vector_type(8))) _Float16;
using half4   = __attribute__((ext_vector_type(4))) _Float16;

__device__ __forceinline__ void gload16(const char* g, char* l) {
    __builtin_amdgcn_global_load_lds(
        (const __attribute__((address_space(1))) unsigned int*)g,
        (__attribute__((address_space(3))) unsigned int*)l, 16, 0, 0);
}

// ---------------------------------------------------------------------------
// W pre-pass: w_in f32 [256][40960] -> Wws f16, 640 chunks of 32 KB; chunk C
// covers k [C*64, C*64+64): byte(r, g) = C*32768 + r*128 + ((g^((r>>1)&7))<<4)
// (granule g = 8 consecutive k-halves, 0..7).
// ---------------------------------------------------------------------------
__global__ __launch_bounds__(256) void nnue_wprep64(
    const float* __restrict__ w_in, _Float16* __restrict__ Wws)
{
    const int C   = blockIdx.x;                 // 0..639
    char* base = (char*)Wws + (size_t)C * WCHUNK_BYTES;
    const int tid = threadIdx.x;
#pragma unroll
    for (int i = 0; i < 8; ++i) {
        const int S = tid + i * 256;            // 0..2047
        const int r = S >> 3, g = S & 7;
        const float* src = w_in + (size_t)r * FEAT + C * 64 + g * 8;
        floatx4 v0 = *reinterpret_cast<const floatx4*>(src);
        floatx4 v1 = *reinterpret_cast<const floatx4*>(src + 4);
        half8 h;
#pragma unroll
        for (int j = 0; j < 4; ++j) { h[j] = (_Float16)v0[j]; h[4 + j] = (_Float16)v1[j]; }
        *reinterpret_cast<half8*>(base + r * 128 + ((g ^ ((r >> 1) & 7)) << 4)) = h;
    }
}

// ---------------------------------------------------------------------------
// Primary GEMM: BM=128 BN=256, 1024 thr = 16 waves (4M x 4N, wave tile 32x64).
// ---------------------------------------------------------------------------
template <typename PT>
__global__ __launch_bounds__(1024, 4) void nnue_gemm_v8(
    const float* __restrict__ white, const float* __restrict__ black,
    const _Float16* __restrict__ Wws, PT* __restrict__ P)
{
    __shared__ __align__(16) _Float16 As[2][128 * 128];   // 64 KB
    __shared__ __align__(16) _Float16 Ws[3][256 * 64];    // 96 KB

    const int tid  = threadIdx.x;
    const int lane = tid & 63;
    const int wave = tid >> 6;    // 0..15
    const int wm   = wave >> 2;   // 0..3 (M, 32 rows each)
    const int wn   = wave & 3;    // 0..3 (N, 64 cols each)

    const int ks = blockIdx.x & 3;    // XCD-aligned K-split
    const int mb = blockIdx.x >> 2;   // 0..63

    const float* Abase = (mb < 32)
        ? (white + (size_t)mb * 128 * FEAT)
        : (black + (size_t)(mb - 32) * 128 * FEAT);
    const int k0 = ks * KCHUNK4;

    // A staging: super-tile 128 rows x 128 f32. Thread chunk j (0..3):
    // row_j = (tid>>5)+32j, col4 = tid&31 -> 512 B contiguous per row-chunk.
    const float* Arow = Abase + (size_t)(tid >> 5) * FEAT + (tid & 31) * 4;
    // LDS f16 [128][128]: byte = row*256 + ((col4*8) ^ ((row>>1&7)<<4));
    // (row_j>>1)&7 == (wave&7) for all j.
    const int aoff = (tid >> 5) * 256 + (((tid & 31) * 8) ^ ((wave & 7) << 4));

    // fragment geometry (mfma_f32_16x16x32_f16):
    // operand: lane reads row (lane&15), 16 B at k-halves (lane>>4)*8
    const int frow = lane & 15;
    const int fhi  = lane >> 4;
    const int swzr = ((frow >> 1) & 7) << 4;

    // W async staging: per-lane global src (pre-swizzled image), linear LDS
    const char* wsrc0 = (const char*)Wws + (size_t)(ks * 160) * WCHUNK_BYTES
                        + wave * 2048 + lane * 16;

    floatx4 acc[2][4];
    const floatx4 zero = {0.f, 0.f, 0.f, 0.f};
#pragma unroll
    for (int m = 0; m < 2; ++m)
#pragma unroll
        for (int n = 0; n < 4; ++n) acc[m][n] = zero;

    floatx4 rc0, rc1, rc2, rc3;   // one 16-VGPR chunk set, statically named

    auto issueW = [&](int T, int wb) {            // T = BK64 index within chunk
        const char* g = wsrc0 + (size_t)T * WCHUNK_BYTES;
        char* l = (char*)&Ws[wb][0] + wave * 2048;
        gload16(g, l);
        gload16(g + 1024, l + 1024);
    };

    auto issueA = [&](floatx4& rc, int j, int kg) {
        rc = *reinterpret_cast<const floatx4*>(Arow + (size_t)j * 32 * FEAT + kg);
    };

    auto cvtStore = [&](floatx4& rc, int j, int ab) {
        half4 h;
#pragma unroll
        for (int jj = 0; jj < 4; ++jj) h[jj] = (_Float16)rc[jj];   // RNE
        *reinterpret_cast<half4*>(
            reinterpret_cast<char*>(&As[ab][0]) + aoff + j * 8192) = h;
    };

    auto mfmaSub = [&](int ab, int cLit, int wb) {
        const char* wbase = (const char*)&Ws[wb][0];
        const char* abase = (const char*)&As[ab][0];
#pragma unroll
        for (int kk = 0; kk < 2; ++kk) {
            half8 bf[4];
#pragma unroll
            for (int n = 0; n < 4; ++n) {
                const int r = wn * 64 + n * 16 + frow;
                bf[n] = *reinterpret_cast<const half8*>(
                    wbase + r * 128 + ((kk * 64 + fhi * 16) ^ swzr));
            }
#pragma unroll
            for (int m = 0; m < 2; ++m) {
                const int row = wm * 32 + m * 16 + frow;
                half8 af = *reinterpret_cast<const half8*>(
                    abase + row * 256 + ((cLit * 128 + kk * 64 + fhi * 16) ^ swzr));
#pragma unroll
                for (int n = 0; n < 4; ++n)
                    acc[m][n] = __builtin_amdgcn_mfma_f32_16x16x32_f16(af, bf[n], acc[m][n], 0, 0, 0);
            }
        }
    };

    // ---- prologue: W(0),W(1) in flight; A super-0 staged; A super-1 in flight
    issueW(0, 0);
    issueW(1, 1);
    __builtin_amdgcn_sched_barrier(0);
    issueA(rc0, 0, k0); issueA(rc1, 1, k0); issueA(rc2, 2, k0); issueA(rc3, 3, k0);
    cvtStore(rc0, 0, 0); cvtStore(rc1, 1, 0); cvtStore(rc2, 2, 0); cvtStore(rc3, 3, 0);
    issueA(rc0, 0, k0 + 128); issueA(rc1, 1, k0 + 128);
    issueA(rc2, 2, k0 + 128); issueA(rc3, 3, k0 + 128);
    asm volatile("s_waitcnt lgkmcnt(0)" ::: "memory");
    __builtin_amdgcn_s_barrier();
    __builtin_amdgcn_sched_barrier(0);

    // ---- main loop: supers s = 0..77 (full body). T = 2s + c.
    int wr0 = 0;   // (2s)%3, advanced by +2 mod 3 each super
    for (int s = 0; s < 78; ++s) {
        const int abR = s & 1;
        const int abW = abR ^ 1;
        const int wr1 = (wr0 + 1) % 3;      // (2s+1)%3
        const int wb0 = (wr0 + 2) % 3;      // (2s+2)%3
        const int kg  = k0 + (s + 2) * 128;
        // sub c=0
        issueW(2 * s + 2, wb0);
        __builtin_amdgcn_sched_barrier(0);
        mfmaSub(abR, 0, wr0);
        cvtStore(rc0, 0, abW); cvtStore(rc1, 1, abW);
        issueA(rc0, 0, kg); issueA(rc1, 1, kg);
        asm volatile("s_waitcnt vmcnt(6) lgkmcnt(0)" ::: "memory");
        __builtin_amdgcn_s_barrier();
        __builtin_amdgcn_sched_barrier(0);
        // sub c=1
        issueW(2 * s + 3, wr0);             // (2s+3)%3 == (2s)%3
        __builtin_amdgcn_sched_barrier(0);
        mfmaSub(abR, 1, wr1);
        cvtStore(rc2, 2, abW); cvtStore(rc3, 3, abW);
        issueA(rc2, 2, kg); issueA(rc3, 3, kg);
        asm volatile("s_waitcnt vmcnt(6) lgkmcnt(0)" ::: "memory");
        __builtin_amdgcn_s_barrier();
        __builtin_amdgcn_sched_barrier(0);
        wr0 = (wr0 + 2) % 3;
    }

    // ---- peel s=78 (T=156,157; reads As[0]; stores super-79 -> As[1])
    // 156%3=0, 157%3=1, 158%3=2, 159%3=0
    issueW(158, 2);
    __builtin_amdgcn_sched_barrier(0);
    mfmaSub(0, 0, 0);
    cvtStore(rc0, 0, 1); cvtStore(rc1, 1, 1);
    asm volatile("s_waitcnt vmcnt(4) lgkmcnt(0)" ::: "memory");
    __builtin_amdgcn_s_barrier();
    __builtin_amdgcn_sched_barrier(0);
    issueW(159, 0);
    __builtin_amdgcn_sched_barrier(0);
    mfmaSub(0, 1, 1);
    cvtStore(rc2, 2, 1); cvtStore(rc3, 3, 1);
    asm volatile("s_waitcnt vmcnt(2) lgkmcnt(0)" ::: "memory");
    __builtin_amdgcn_s_barrier();
    __builtin_amdgcn_sched_barrier(0);
    // ---- peel s=79 (T=158,159; reads As[1])
    mfmaSub(1, 0, 2);
    asm volatile("s_waitcnt vmcnt(0) lgkmcnt(0)" ::: "memory");
    __builtin_amdgcn_s_barrier();
    __builtin_amdgcn_sched_barrier(0);
    mfmaSub(1, 1, 0);

    // ---- epilogue: partial C (pre-bias, pre-clip) to workspace
    PT* Pb = P + (size_t)ks * PSTRIDE + (size_t)mb * 128 * 256;
#pragma unroll
    for (int m = 0; m < 2; ++m)
#pragma unroll
        for (int n = 0; n < 4; ++n)
#pragma unroll
            for (int r = 0; r < 4; ++r) {
                const int row = wm * 32 + m * 16 + fhi * 4 + r;
                const int col = wn * 64 + n * 16 + frow;
                Pb[(size_t)row * 256 + col] = (PT)acc[m][n][r];
            }
}

// ---------------------------------------------------------------------------
// Tail: reduce KS partials + b_in + clip -> x[.,512], then the 3 tiny layers.
// One block per 32 batch rows.
// ---------------------------------------------------------------------------
template <typename PT>
__global__ __launch_bounds__(256) void nnue_tail(
    const PT* __restrict__ P, int KS,
    const float* __restrict__ b_in,
    const float* __restrict__ w_h1, const float* __restrict__ b_h1,
    const float* __restrict__ w_h2, const float* __restrict__ b_h2,
    const float* __restrict__ w_out, const float* __restrict__ b_out,
    float* __restrict__ out)
{
    __shared__ float xs[32][512];
    __shared__ float w1[32][513];
    __shared__ float w2[32][33];
    __shared__ float h1[32][33];
    __shared__ float h2[32][33];
    __shared__ float wo[32];

    const int tid = threadIdx.x;
    const int b0  = blockIdx.x * 32;

    for (int i = tid; i < 32 * 512; i += 256) w1[i >> 9][i & 511] = w_h1[i];
    for (int i = tid; i < 32 * 32; i += 256)  w2[i >> 5][i & 31]  = w_h2[i];
    if (tid < 32) wo[tid] = w_out[tid];

    for (int i = tid; i < 32 * 512; i += 256) {
        const int r = i >> 9, c = i & 511;
        const int persp = c >> 8, n = c & 255;
        const size_t prow = (size_t)(b0 + r) + (persp ? 4096u : 0u);
        float v = 0.f;
        for (int s = 0; s < KS; ++s)
            v += (float)P[(size_t)s * PSTRIDE + prow * 256 + n];
        v += b_in[n];
        xs[r][c] = fminf(fmaxf(v, 0.f), 1.f);
    }
    __syncthreads();

    for (int p = tid; p < 32 * 32; p += 256) {
        const int o = p & 31, r = p >> 5;
        float a = b_h1[o];
        for (int j = 0; j < 512; ++j) a += xs[r][j] * w1[o][j];
        h1[r][o] = fminf(fmaxf(a, 0.f), 1.f);
    }
    __syncthreads();

    for (int p = tid; p < 32 * 32; p += 256) {
        const int o = p & 31, r = p >> 5;
        float a = b_h2[o];
        for (int j = 0; j < 32; ++j) a += h1[r][j] * w2[o][j];
        h2[r][o] = fminf(fmaxf(a, 0.f), 1.f);
    }
    __syncthreads();

    if (tid < 32) {
        float a = b_out[0];
        for (int j = 0; j < 32; ++j) a += h2[tid][j] * wo[j];
        out[b0 + tid] = a;
    }
}

// ---------------------------------------------------------------------------
// Emergency fallback (ws too small): slow but correct, no scratch.
// ---------------------------------------------------------------------------
__global__ __launch_bounds__(256) void nnue_naive(
    const float* __restrict__ white, const float* __restrict__ black,
    const float* __restrict__ w_in, const float* __restrict__ b_in,
    const float* __restrict__ w_h1, const float* __restrict__ b_h1,
    const float* __restrict__ w_h2, const float* __restrict__ b_h2,
    const float* __restrict__ w_out, const float* __restrict__ b_out,
    float* __restrict__ out)
{
    __shared__ float feat[4096];
    __shared__ float xs[512];
    __shared__ float h1s[32];
    __shared__ float h2s[32];
    const int b = blockIdx.x, tid = threadIdx.x;
    float acc0 = 0.f, acc1 = 0.f;
    for (int c = 0; c < FEAT; c += 2048) {
        for (int i = tid; i < 2048; i += 256) {
            feat[i]        = white[(size_t)b * FEAT + c + i];
            feat[2048 + i] = black[(size_t)b * FEAT + c + i];
        }
        __syncthreads();
        const float* wr = w_in + (size_t)tid * FEAT + c;
        for (int k = 0; k < 2048; ++k) {
            const float w = wr[k];
            acc0 += feat[k] * w;
            acc1 += feat[2048 + k] * w;
        }
        __syncthreads();
    }
    xs[tid]       = fminf(fmaxf(acc0 + b_in[tid], 0.f), 1.f);
    xs[256 + tid] = fminf(fmaxf(acc1 + b_in[tid], 0.f), 1.f);
    __syncthreads();
    if (tid < 32) {
        float a = b_h1[tid];
        for (int j = 0; j < 512; ++j) a += xs[j] * w_h1[tid * 512 + j];
        h1s[tid] = fminf(fmaxf(a, 0.f), 1.f);
    }
    __syncthreads();
    if (tid < 32) {
        float a = b_h2[tid];
        for (int j = 0; j < 32; ++j) a += h1s[j] * w_h2[tid * 32 + j];
        h2s[tid] = fminf(fmaxf(a, 0.f), 1.f);
    }
    __syncthreads();
    if (tid == 0) {
        float a = b_out[0];
        for (int j = 0; j < 32; ++j) a += h2s[j] * w_out[j];
        out[b] = a;
    }
}

extern "C" void kernel_launch(void* const* d_in, const int* in_sizes, int n_in,
                              void* d_out, int out_size, void* d_ws, size_t ws_size,
                              hipStream_t stream)
{
    const float* white = (const float*)d_in[0];
    const float* black = (const float*)d_in[1];
    const float* w_in  = (const float*)d_in[2];
    const float* b_in  = (const float*)d_in[3];
    const float* w_h1  = (const float*)d_in[4];
    const float* b_h1  = (const float*)d_in[5];
    const float* w_h2  = (const float*)d_in[6];
    const float* b_h2  = (const float*)d_in[7];
    const float* w_out = (const float*)d_in[8];
    const float* b_out = (const float*)d_in[9];
    float* out = (float*)d_out;

    const size_t pF32 = KS4 * PSTRIDE * sizeof(float);     // 32 MB
    const size_t pF16 = KS4 * PSTRIDE * sizeof(_Float16);  // 16 MB

    if (ws_size >= pF32 + WWS_BYTES) {
        float* P = (float*)d_ws;
        _Float16* Wws = (_Float16*)((char*)d_ws + pF32);
        nnue_wprep64<<<dim3(NWCHUNK), 256, 0, stream>>>(w_in, Wws);
        nnue_gemm_v8<float><<<dim3(256), 1024, 0, stream>>>(white, black, Wws, P);
        nnue_tail<float><<<dim3(128), 256, 0, stream>>>(P, KS4, b_in, w_h1, b_h1,
                                                        w_h2, b_h2, w_out, b_out, out);
    } else if (ws_size >= pF16 + WWS_BYTES) {
        _Float16* P = (_Float16*)d_ws;
        _Float16* Wws = (_Float16*)((char*)d_ws + pF16);
        nnue_wprep64<<<dim3(NWCHUNK), 256, 0, stream>>>(w_in, Wws);
        nnue_gemm_v8<_Float16><<<dim3(256), 1024, 0, stream>>>(white, black, Wws, P);
        nnue_tail<_Float16><<<dim3(128), 256, 0, stream>>>(P, KS4, b_in, w_h1, b_h1,
                                                           w_h2, b_h2, w_out, b_out, out);
    } else {
        nnue_naive<<<4096, 256, 0, stream>>>(white, black, w_in, b_in, w_h1, b_h1,
                                             w_h2, b_h2, w_out, b_out, out);
    }
}